// Round 9
// baseline (962.585 us; speedup 1.0000x reference)
//
#include <hip/hip_runtime.h>
#include <hip/hip_bf16.h>

typedef short v8s __attribute__((ext_vector_type(8)));
typedef float v4f __attribute__((ext_vector_type(4)));
typedef unsigned short bf16u;

#define NB    32
#define NCDD  5
#define NHIS  50
#define NL    32
#define NE    300
#define NEP   320
#define NH    16
#define NQD   200
#define NR    256
#define NMASK 40
#define NITEM 1760
#define SCALE 0.05773502691896258f  /* 1/sqrt(300) */

// workspace offsets (bytes), all 256-aligned
#define WQB_OFF  0u          /* wqB [16][320][320] bf16 = 3,276,800 ([h][e][f]) */
#define WVT_OFF  3276800u    /* wvT [16][16][320]  bf16 =   163,840 */
#define WKT_OFF  3440640u    /* wkT [256][256]     bf16 =   131,072 */
#define REP_OFF  3571712u    /* rep [1760][256]    f32  = 1,802,240 */
#define HVAL_OFF 5373952u    /* hval [1760][32][256] bf16 = 28,835,840 */

#define XS  328  /* x LDS row stride: 656B -> 2-way bank step (free) */
#define TS  40   /* wave scratch row stride: 80B -> 2-way (free), 16B-aligned */
#define XVS 40   /* xv row stride: 80B */
#define VS  264  /* val row stride: 528B, 16B-aligned */

__device__ __forceinline__ float b2f(bf16u u) {
  return __uint_as_float(((unsigned int)u) << 16);
}
// native RNE convert -- bit-identical to manual RNE (R7: absmax unchanged);
// compiler fuses adjacent casts into v_cvt_pk_bf16_f32.
__device__ __forceinline__ bf16u f2b(float f) {
  __hip_bfloat16 h = __float2bfloat16(f);
  return *reinterpret_cast<bf16u*>(&h);
}

#define MFMA(a, b, c) __builtin_amdgcn_mfma_f32_16x16x32_bf16((a), (b), (c), 0, 0, 0)
#define Z4 ((v4f){0.f, 0.f, 0.f, 0.f})
#define PACKU2(p, t)                                                      \
  do {                                                                    \
    (p).x = (unsigned)f2b((t)[0]) | ((unsigned)f2b((t)[1]) << 16);        \
    (p).y = (unsigned)f2b((t)[2]) | ((unsigned)f2b((t)[3]) << 16);        \
  } while (0)

// ---------------------------------------------------------------------------
// prep: f32 weights -> bf16, zero-padded.
// ---------------------------------------------------------------------------
__global__ void prep_kernel(const float* __restrict__ wq,
                            const float* __restrict__ wvp,
                            const float* __restrict__ wk,
                            bf16u* __restrict__ wqB,
                            bf16u* __restrict__ wvT,
                            bf16u* __restrict__ wkT) {
  int idx = blockIdx.x * 256 + threadIdx.x;
  const int N1 = 16 * 320 * 320;
  const int N2 = 16 * 16 * 320;
  const int N3 = 256 * 256;
  if (idx < N1) {
    int h = idx / (320 * 320);
    int r = idx % (320 * 320);
    int e = r / 320, f = r % 320;
    wqB[idx] = (e < NE && f < NE) ? f2b(wq[h * 90000 + e * 300 + f]) : (bf16u)0;
  } else if (idx < N1 + N2) {
    int i = idx - N1;
    int h = i / (16 * 320);
    int r = i % (16 * 320);
    int v = r / 320, e = r % 320;
    wvT[i] = (e < NE) ? f2b(wvp[h * 4800 + e * 16 + v]) : (bf16u)0;
  } else if (idx < N1 + N2 + N3) {
    int i = idx - N1 - N2;
    int d = i / 256, rr = i % 256;
    wkT[i] = (d < NQD) ? f2b(wk[rr * 200 + d]) : (bf16u)0;
  }
}

// ---------------------------------------------------------------------------
// encode: grid = 1760 items; 512 thr (8 waves); 69.2 KB LDS -> 2 blocks/CU.
// ROUND-9: the untested matrix cell (1-item, 2 blk/CU, barrier-free).
// Evidence: throughput tracks resident waves (R8: 4 waves = 1.36x worse than
// R4's 8); barrier-free removed R0->R4's phase-idling (692->553); R2 proved
// the 1-item register profile fits (512,4) with ZERO spill (52 arch VGPR) --
// the only structure that ever fit the 128-reg budget. This combines all
// three: each wave owns 2 heads end-to-end (R4 chunk loop with the item
// dimension deleted: t[2][2]+s[2][2] = 64 acc regs = exactly the AGPR half);
// 16 waves/CU = 4/SIMD, double R4's latency hiding at equal per-CU pipe
// work. Wq L2 traffic doubles (~1.4 TB/s/XCD << ~4.3 ceiling) -- we are
// latency-bound, not L2-BW-bound. All index expressions verbatim from
// verified kernels (R4 i=0; R3 1-item softmax/xv/v; R2 1-item tail).
// ---------------------------------------------------------------------------
__global__ __launch_bounds__(512, 4) void encode_kernel(
    const int* __restrict__ cand_tok, const int* __restrict__ clk_tok,
    const float* __restrict__ emb,
    const bf16u* __restrict__ wqB, const bf16u* __restrict__ wvT,
    const bf16u* __restrict__ wkT,
    const float* __restrict__ bk, const float* __restrict__ qw,
    float* __restrict__ rep, bf16u* __restrict__ hval) {
  __shared__ alignas(16) bf16u x_s[32 * XS];        // 20,992 B
  __shared__ alignas(16) bf16u scr_s[8][32 * TS];   // 20,480 B (per-wave)
  __shared__ alignas(16) bf16u xv_s[8][16 * XVS];   // 10,240 B (per-wave)
  __shared__ alignas(16) bf16u val_s[32 * VS];      // 16,896 B
  __shared__ float wl_s[4][32];                     //    512 B
  __shared__ float ww_s[32];                        //    128 B
  // total 69,248 B -> 2 blocks/CU (2 x 69,248 <= 163,840)

  const int tid = threadIdx.x;
  const int lane = tid & 63;
  const int w = tid >> 6;     // wave 0..7
  const int q4 = lane >> 4;
  const int l15 = lane & 15;
  const int g = blockIdx.x;   // item index

  // gather x straight from emb (f32 -> bf16), pad cols 300..327 (R2 verbatim)
  for (int c = tid; c < 32 * 82; c += 512) {
    int l = c / 82, j = c % 82;
    bf16u tmp[4] = {0, 0, 0, 0};
    if (j < 75) {
      int tok = (g < NB * NCDD) ? cand_tok[g * NL + l]
                                : clk_tok[(g - NB * NCDD) * NL + l];
      float4 d = *(const float4*)(emb + (size_t)tok * NE + j * 4);
      tmp[0] = f2b(d.x); tmp[1] = f2b(d.y); tmp[2] = f2b(d.z); tmp[3] = f2b(d.w);
    }
    *(uint2*)(&x_s[l * XS + j * 4]) = *(const uint2*)tmp;
  }
  __syncthreads();

  bf16u* tb = &scr_s[w][0];   // wave scratch [32 rows][TS]
  bf16u* xvb = &xv_s[w][0];   // wave xv [16 v][XVS]

#pragma unroll 1
  for (int hh = 0; hh < 2; ++hh) {
    const int h = (w << 1) | hh;
    const bf16u* wqh = wqB + (size_t)h * 102400;

    // s accumulators: [l-tile][m-tile], 4 independent MFMA chains
    v4f s[2][2];
#pragma unroll
    for (int lt = 0; lt < 2; ++lt)
#pragma unroll
      for (int mt = 0; mt < 2; ++mt) s[lt][mt] = Z4;

#pragma unroll 1
    for (int ch = 0; ch < 10; ++ch) {
      // ---- t-chunk: t[e=ch*32..+31][tok 0..31] = Wq @ x^T (contract f) ----
      v4f t[2][2];  // [e-tile j][tok-tile tt]
#pragma unroll
      for (int j = 0; j < 2; ++j)
#pragma unroll
        for (int tt = 0; tt < 2; ++tt) t[j][tt] = Z4;
      const bf16u* ap = wqh + (size_t)(ch * 32 + l15) * NEP + q4 * 8;
#pragma unroll
      for (int ks = 0; ks < 10; ++ks) {
        v8s a0 = *(const v8s*)(ap + ks * 32);             // e rows ch*32+0..15
        v8s a1 = *(const v8s*)(ap + 16 * NEP + ks * 32);  // e rows +16..31
        v8s b0 = *(const v8s*)(&x_s[l15 * XS + ks * 32 + q4 * 8]);
        v8s b1 = *(const v8s*)(&x_s[(16 + l15) * XS + ks * 32 + q4 * 8]);
        t[0][0] = MFMA(a0, b0, t[0][0]); t[0][1] = MFMA(a0, b1, t[0][1]);
        t[1][0] = MFMA(a1, b0, t[1][0]); t[1][1] = MFMA(a1, b1, t[1][1]);
      }
      // pack: acc col=l15=tok-in-tile, rows=4 consecutive e -> scratch
      // [tok-row][e-local], 8B-aligned writes (R4-verbatim, i=0)
#pragma unroll
      for (int j = 0; j < 2; ++j)
#pragma unroll
        for (int tt = 0; tt < 2; ++tt) {
          uint2 p;
          PACKU2(p, t[j][tt]);
          *(uint2*)(tb + (tt * 16 + l15) * TS + j * 16 + q4 * 4) = p;
        }
      // ---- s(ch): s[l][m] += tT[l][e-chunk] * x[m][e-chunk] ----
#pragma unroll
      for (int lt = 0; lt < 2; ++lt) {
        v8s ta = *(const v8s*)(tb + (lt * 16 + l15) * TS + q4 * 8);
#pragma unroll
        for (int mt = 0; mt < 2; ++mt) {
          v8s xb = *(const v8s*)(
              &x_s[(mt * 16 + l15) * XS + ch * 32 + q4 * 8]);
          s[lt][mt] = MFMA(ta, xb, s[lt][mt]);
        }
      }
    }

    // ---- s -> scratch (bf16 [l-row][m-col]; R4-verbatim, i=0) ----
#pragma unroll
    for (int lt = 0; lt < 2; ++lt)
#pragma unroll
      for (int mt = 0; mt < 2; ++mt)
#pragma unroll
        for (int r = 0; r < 4; ++r)
          tb[(lt * 16 + q4 * 4 + r) * TS + mt * 16 + l15] = f2b(s[lt][mt][r]);

    // ---- softmax over m, in-place (R3's verified 1-item pattern) ----
#pragma unroll
    for (int p = 0; p < 2; ++p) {
      int row = p * 16 + (lane >> 2);
      int jj = lane & 3;
      v8s sv = *(const v8s*)(tb + row * TS + jj * 8);
      float v[8];
      float mx = -1e30f;
#pragma unroll
      for (int k = 0; k < 8; ++k) {
        v[k] = b2f((bf16u)sv[k]) * SCALE;
        mx = fmaxf(mx, v[k]);
      }
      mx = fmaxf(mx, __shfl_xor(mx, 1));
      mx = fmaxf(mx, __shfl_xor(mx, 2));
      float sum = 0.f;
#pragma unroll
      for (int k = 0; k < 8; ++k) { v[k] = __expf(v[k] - mx); sum += v[k]; }
      sum += __shfl_xor(sum, 1);
      sum += __shfl_xor(sum, 2);
      float inv = 1.f / sum;
      bf16u tmp[8];
#pragma unroll
      for (int k = 0; k < 8; ++k) tmp[k] = f2b(v[k] * inv);
      *(uint4*)(tb + row * TS + jj * 8) = *(const uint4*)tmp;
    }

    // ---- xv = x @ WvT[h] -> xv_s [v][tok32] (R3-verbatim layout) ----
    {
      v4f xa[2];  // [m-tile]
#pragma unroll
      for (int mt = 0; mt < 2; ++mt) xa[mt] = Z4;
      const bf16u* vb = wvT + (size_t)h * (16 * NEP) + l15 * NEP + q4 * 8;
#pragma unroll
      for (int ks = 0; ks < 10; ++ks) {
        v8s b = *(const v8s*)(vb + ks * 32);
#pragma unroll
        for (int mt = 0; mt < 2; ++mt) {
          v8s a = *(const v8s*)(
              &x_s[(mt * 16 + l15) * XS + ks * 32 + q4 * 8]);
          xa[mt] = MFMA(a, b, xa[mt]);
        }
      }
      // acc col=l15=v, rows=4 toks -> [v-row l15][tok-col]
#pragma unroll
      for (int mt = 0; mt < 2; ++mt) {
        uint2 p;
        PACKU2(p, xa[mt]);
        *(uint2*)(xvb + l15 * XVS + mt * 16 + q4 * 4) = p;
      }
    }

    // ---- v = a @ xv -> val_s[:, h*16 + 0..15] (wave-private columns) ----
#pragma unroll
    for (int lt = 0; lt < 2; ++lt) {
      v8s af = *(const v8s*)(tb + (lt * 16 + l15) * TS + q4 * 8);
      v8s bv = *(const v8s*)(xvb + l15 * XVS + q4 * 8);
      v4f vv = MFMA(af, bv, Z4);
#pragma unroll
      for (int r = 0; r < 4; ++r)
        val_s[(lt * 16 + q4 * 4 + r) * VS + h * 16 + l15] = f2b(vv[r]);
    }
  }
  __syncthreads();

  // ---- keyw = tanh(val@WkT + bk); wl = SCALE * qw . keyw (R2 verbatim) ----
  // 8 waves: lt = token half, half/kq split the 256 output d's 4 ways.
  {
    int lt = w >> 2, half = (w >> 1) & 1, kq = w & 1;
    const bf16u* vrow = &val_s[(lt * 16 + l15) * VS + q4 * 8];
    v8s af2[8];
#pragma unroll
    for (int ks = 0; ks < 8; ++ks) af2[ks] = *(const v8s*)(vrow + ks * 32);
    float wlp[4] = {0.f, 0.f, 0.f, 0.f};
#pragma unroll
    for (int k = 0; k < 4; ++k) {
      int d = (half * 8 + kq * 4 + k) * 16 + l15;
      float bkf = (d < NQD) ? bk[d] : 0.f;
      float qwf = (d < NQD) ? qw[d] : 0.f;
      v4f acc = Z4;
      const bf16u* bp2 = wkT + d * NR + q4 * 8;
#pragma unroll
      for (int ks = 0; ks < 8; ++ks) {
        v8s b = *(const v8s*)(bp2 + ks * 32);
        acc = MFMA(af2[ks], b, acc);
      }
#pragma unroll
      for (int r = 0; r < 4; ++r)
        wlp[r] += tanhf(acc[r] + bkf) * qwf;
    }
#pragma unroll
    for (int r = 0; r < 4; ++r) {
      float tv = wlp[r] * SCALE;
      tv += __shfl_xor(tv, 1);
      tv += __shfl_xor(tv, 2);
      tv += __shfl_xor(tv, 4);
      tv += __shfl_xor(tv, 8);
      if (l15 == 0) wl_s[half * 2 + kq][lt * 16 + q4 * 4 + r] = tv;
    }
  }
  __syncthreads();

  // ---- ww = softmax(wl) (lanes 0-31 of wave 0) ----
  if (tid < 32) {
    float v = wl_s[0][tid] + wl_s[1][tid] + wl_s[2][tid] + wl_s[3][tid];
    float mx = v;
#pragma unroll
    for (int off = 1; off < 32; off <<= 1) mx = fmaxf(mx, __shfl_xor(mx, off, 32));
    float e = __expf(v - mx);
    float sum = e;
#pragma unroll
    for (int off = 1; off < 32; off <<= 1) sum += __shfl_xor(sum, off, 32);
    ww_s[tid] = e / sum;
  }
  __syncthreads();

  // ---- rep[r] = sum_l ww[l]*val[l][r] ----
  if (tid < 256) {
    const bf16u* vb2 = &val_s[tid];
    float sv = 0.f;
#pragma unroll 8
    for (int l = 0; l < 32; ++l) sv += ww_s[l] * b2f(vb2[l * VS]);
    rep[(size_t)g * NR + tid] = sv;
  }
  // ---- hval writeback (clicked items only), coalesced uint4 ----
  if (g >= NB * NCDD) {
    for (int c = tid; c < 1024; c += 512) {
      int l = c >> 5, j = c & 31;
      *(uint4*)(hval + (size_t)g * (NL * NR) + l * NR + j * 8) =
          *(const uint4*)(&val_s[l * VS + j * 8]);
    }
  }
}

// ---------------------------------------------------------------------------
// select: one block per (b,c): score[h] = cdd_rep.his_rep + gumbel (h<40),
// argmax, gather. grid = 160.
// ---------------------------------------------------------------------------
__global__ __launch_bounds__(256) void select_kernel(
    const float* __restrict__ rep, const float* __restrict__ gumbel,
    const bf16u* __restrict__ hval, float* __restrict__ out) {
  __shared__ float score[NMASK];
  __shared__ int hstar;
  const float* cdd_rep = rep;
  const float* his_rep = rep + (size_t)(NB * NCDD) * NR;
  const bf16u* his_val = hval + (size_t)(NB * NCDD) * (NL * NR);
  int b = blockIdx.x / NCDD, c = blockIdx.x % NCDD;
  int tid = threadIdx.x, lane = tid & 63, wv = tid >> 6;
  const float* cr = cdd_rep + (size_t)(b * NCDD + c) * NR;
  for (int h = wv; h < NMASK; h += 4) {
    const float* hr = his_rep + (size_t)(b * NHIS + h) * NR;
    float s = 0.f;
#pragma unroll
    for (int j = 0; j < 4; ++j) s += cr[lane * 4 + j] * hr[lane * 4 + j];
#pragma unroll
    for (int off = 1; off < 64; off <<= 1) s += __shfl_xor(s, off);
    if (lane == 0)
      score[h] = s + gumbel[(b * NCDD + c) * NHIS + h];
  }
  __syncthreads();
  if (tid == 0) {
    float best = -1e30f;
    int bi = 0;
    for (int h = 0; h < NMASK; ++h) {
      float v = score[h];
      if (v > best) { best = v; bi = h; }  // strict > keeps first max
    }
    hstar = bi;
  }
  __syncthreads();
  const bf16u* src = his_val + (size_t)(b * NHIS + hstar) * (NL * NR);
  float* dst = out + (size_t)(b * NCDD + c) * (NL * NR);
  for (int k = tid; k < 2048; k += 256) {
    const bf16u* sp = src + k * 4;
    float4 o;
    o.x = b2f(sp[0]); o.y = b2f(sp[1]); o.z = b2f(sp[2]); o.w = b2f(sp[3]);
    *(float4*)(dst + k * 4) = o;
  }
}

extern "C" void kernel_launch(void* const* d_in, const int* in_sizes, int n_in,
                              void* d_out, int out_size, void* d_ws, size_t ws_size,
                              hipStream_t stream) {
  (void)in_sizes; (void)n_in; (void)out_size; (void)ws_size;
  const int* cand = (const int*)d_in[0];
  const int* clk = (const int*)d_in[1];
  // d_in[2] his_mask (static: h>=40), d_in[3]/d_in[4] pads: unused
  const float* gum = (const float*)d_in[5];
  const float* emb = (const float*)d_in[6];
  const float* wq = (const float*)d_in[7];
  const float* wvp = (const float*)d_in[8];
  const float* wk = (const float*)d_in[9];
  const float* bk = (const float*)d_in[10];
  const float* qw = (const float*)d_in[11];

  char* ws = (char*)d_ws;
  bf16u* wqB = (bf16u*)(ws + WQB_OFF);
  bf16u* wvT = (bf16u*)(ws + WVT_OFF);
  bf16u* wkT = (bf16u*)(ws + WKT_OFF);
  float* rep = (float*)(ws + REP_OFF);
  bf16u* hval = (bf16u*)(ws + HVAL_OFF);

  const int totalT = 16 * 320 * 320 + 16 * 16 * 320 + 256 * 256;  // 1,785,856
  hipLaunchKernelGGL(prep_kernel, dim3((totalT + 255) / 256), dim3(256), 0, stream,
                     wq, wvp, wk, wqB, wvT, wkT);
  hipLaunchKernelGGL(encode_kernel, dim3(NITEM), dim3(512), 0, stream,
                     cand, clk, emb, wqB, wvT, wkT, bk, qw, rep, hval);
  hipLaunchKernelGGL(select_kernel, dim3(NB * NCDD), dim3(256), 0, stream,
                     rep, gum, hval, (float*)d_out);
}

// Round 10
// 627.963 us; speedup vs baseline: 1.5329x; 1.5329x over previous
//
#include <hip/hip_runtime.h>
#include <hip/hip_bf16.h>

typedef short v8s __attribute__((ext_vector_type(8)));
typedef float v4f __attribute__((ext_vector_type(4)));
typedef unsigned short bf16u;

#define NB    32
#define NCDD  5
#define NHIS  50
#define NL    32
#define NE    300
#define NEP   320
#define NH    16
#define NQD   200
#define NR    256
#define NMASK 40
#define NITEM 1760
#define SCALE 0.05773502691896258f  /* 1/sqrt(300) */

// workspace offsets (bytes), all 256-aligned
#define WQB_OFF  0u          /* wqB [16][320][320] bf16 = 3,276,800 ([h][e][f]) */
#define WVT_OFF  3276800u    /* wvT [16][16][320]  bf16 =   163,840 */
#define WKT_OFF  3440640u    /* wkT [256][256]     bf16 =   131,072 */
#define REP_OFF  3571712u    /* rep [1760][256]    f32  = 1,802,240 */
#define HVAL_OFF 5373952u    /* hval [1760][32][256] bf16 = 28,835,840 */

#define XS  328  /* x LDS row stride: 656B -> 2-way bank step (free) */
#define TS  40   /* wave scratch row stride: 80B -> 2-way (free), 16B-aligned */
#define TSX 72   /* xv row stride: 144B, 16B-aligned, ~2-way */
#define VS  264  /* val row stride: 528B, 16B-aligned */

__device__ __forceinline__ float b2f(bf16u u) {
  return __uint_as_float(((unsigned int)u) << 16);
}
// native RNE convert -- bit-identical to manual RNE (R7: absmax unchanged);
// compiler fuses adjacent casts into v_cvt_pk_bf16_f32.
__device__ __forceinline__ bf16u f2b(float f) {
  __hip_bfloat16 h = __float2bfloat16(f);
  return *reinterpret_cast<bf16u*>(&h);
}

#define MFMA(a, b, c) __builtin_amdgcn_mfma_f32_16x16x32_bf16((a), (b), (c), 0, 0, 0)
#define Z4 ((v4f){0.f, 0.f, 0.f, 0.f})
#define PACKU2(p, t)                                                      \
  do {                                                                    \
    (p).x = (unsigned)f2b((t)[0]) | ((unsigned)f2b((t)[1]) << 16);        \
    (p).y = (unsigned)f2b((t)[2]) | ((unsigned)f2b((t)[3]) << 16);        \
  } while (0)

// ---------------------------------------------------------------------------
// prep: f32 weights -> bf16, zero-padded.
// ---------------------------------------------------------------------------
__global__ void prep_kernel(const float* __restrict__ wq,
                            const float* __restrict__ wvp,
                            const float* __restrict__ wk,
                            bf16u* __restrict__ wqB,
                            bf16u* __restrict__ wvT,
                            bf16u* __restrict__ wkT) {
  int idx = blockIdx.x * 256 + threadIdx.x;
  const int N1 = 16 * 320 * 320;
  const int N2 = 16 * 16 * 320;
  const int N3 = 256 * 256;
  if (idx < N1) {
    int h = idx / (320 * 320);
    int r = idx % (320 * 320);
    int e = r / 320, f = r % 320;
    wqB[idx] = (e < NE && f < NE) ? f2b(wq[h * 90000 + e * 300 + f]) : (bf16u)0;
  } else if (idx < N1 + N2) {
    int i = idx - N1;
    int h = i / (16 * 320);
    int r = i % (16 * 320);
    int v = r / 320, e = r % 320;
    wvT[i] = (e < NE) ? f2b(wvp[h * 4800 + e * 16 + v]) : (bf16u)0;
  } else if (idx < N1 + N2 + N3) {
    int i = idx - N1 - N2;
    int d = i / 256, rr = i % 256;
    wkT[i] = (d < NQD) ? f2b(wk[rr * 200 + d]) : (bf16u)0;
  }
}

// ---------------------------------------------------------------------------
// encode: grid = 880 2-item blocks; 512 thr (8 waves); 136 KB LDS, 1 blk/CU.
// ROUND-10: R4 (553us, best of 10 rounds; every structural probe around it
// -- occupancy, pipelining, register-budget, item-count -- lost). Two local
// register-light edits on exact-R4:
//  * xv FOLDED into chunk 0 of the t-loop: within one chunk, the ks-loop
//    sweeps all 300 x-cols, and its b0..b3 fragments (x rows=tok, k=slice)
//    are exactly xv's A-operand. Accumulate xa += MFMA(b_frag, wv_frag) in
//    chunk 0 (peeled so xa dies right after -> peak acc 80 regs, then 64),
//    delete the standalone xv phase: -640 DS reads/block + one serial GEMM
//    phase's latency per head.
//  * native __float2bfloat16 (R7: absmax bit-identical) replaces the 5-op
//    manual RNE in pack/s-store/softmax: VALU pipe ~75us -> ~45us.
// All layouts, sync structure, tails, select: R4-verbatim.
// ---------------------------------------------------------------------------
__global__ __launch_bounds__(512, 2) void encode_kernel(
    const int* __restrict__ cand_tok, const int* __restrict__ clk_tok,
    const float* __restrict__ emb,
    const bf16u* __restrict__ wqB, const bf16u* __restrict__ wvT,
    const bf16u* __restrict__ wkT,
    const float* __restrict__ bk, const float* __restrict__ qw,
    float* __restrict__ rep, bf16u* __restrict__ hval) {
  __shared__ alignas(16) bf16u x_s[64 * XS];        // 41,984 B
  __shared__ alignas(16) bf16u scr_s[8][64 * TS];   // 40,960 B (per-wave)
  __shared__ alignas(16) bf16u xv_s[8][16 * TSX];   // 18,432 B (per-wave)
  __shared__ alignas(16) bf16u val_s[2 * 32 * VS];  // 33,792 B
  __shared__ float wl_s[2][64];                     //    512 B
  __shared__ float ww_s[64];                        //    256 B
  // total 135,936 B -> 1 block/CU

  const int tid = threadIdx.x;
  const int lane = tid & 63;
  const int w = tid >> 6;     // wave 0..7
  const int q4 = lane >> 4;
  const int l15 = lane & 15;
  const int g0 = blockIdx.x * 2;

  // gather 2 items of x straight from emb (f32 -> bf16), pad cols 300..327
  for (int c = tid; c < 2 * 32 * 82; c += 512) {
    int item = c / (32 * 82);
    int rr = c % (32 * 82);
    int l = rr / 82, j = rr % 82;
    bf16u tmp[4] = {0, 0, 0, 0};
    if (j < 75) {
      int gi = g0 + item;
      int tok = (gi < NB * NCDD) ? cand_tok[gi * NL + l]
                                 : clk_tok[(gi - NB * NCDD) * NL + l];
      float4 d = *(const float4*)(emb + (size_t)tok * NE + j * 4);
      tmp[0] = f2b(d.x); tmp[1] = f2b(d.y); tmp[2] = f2b(d.z); tmp[3] = f2b(d.w);
    }
    *(uint2*)(&x_s[item * 32 * XS + l * XS + j * 4]) = *(const uint2*)tmp;
  }
  __syncthreads();

  bf16u* tb = &scr_s[w][0];   // wave scratch [64 rows][TS]
  bf16u* xvb = &xv_s[w][0];   // wave xv [16 v][TSX]

  for (int hh = 0; hh < 2; ++hh) {
    const int h = (w << 1) | hh;
    const bf16u* wqh = wqB + (size_t)h * 102400;

    // s accumulators: [item][l-tile][m-tile], 8 independent MFMA chains
    v4f s[2][2][2];
#pragma unroll
    for (int i = 0; i < 2; ++i)
#pragma unroll
      for (int lt = 0; lt < 2; ++lt)
#pragma unroll
        for (int mt = 0; mt < 2; ++mt) s[i][lt][mt] = Z4;

    // ---- chunk 0, peeled: t-chunk FUSED with xv (shares b-frag loads) ----
    {
      v4f t[2][4];  // [e-tile j][tok-tile tt]
      v4f xa[2][2]; // xv acc [item][m-tile] -- lives only in this scope
#pragma unroll
      for (int j = 0; j < 2; ++j)
#pragma unroll
        for (int tt = 0; tt < 4; ++tt) t[j][tt] = Z4;
#pragma unroll
      for (int i = 0; i < 2; ++i)
#pragma unroll
        for (int mt = 0; mt < 2; ++mt) xa[i][mt] = Z4;
      const bf16u* ap = wqh + (size_t)l15 * NEP + q4 * 8;  // ch = 0
      const bf16u* vb = wvT + (size_t)h * (16 * NEP) + l15 * NEP + q4 * 8;
#pragma unroll
      for (int ks = 0; ks < 10; ++ks) {
        v8s a0 = *(const v8s*)(ap + ks * 32);             // e rows 0..15
        v8s a1 = *(const v8s*)(ap + 16 * NEP + ks * 32);  // e rows 16..31
        v8s b0 = *(const v8s*)(&x_s[l15 * XS + ks * 32 + q4 * 8]);
        v8s b1 = *(const v8s*)(&x_s[(16 + l15) * XS + ks * 32 + q4 * 8]);
        v8s b2 = *(const v8s*)(&x_s[(32 + l15) * XS + ks * 32 + q4 * 8]);
        v8s b3 = *(const v8s*)(&x_s[(48 + l15) * XS + ks * 32 + q4 * 8]);
        v8s wf = *(const v8s*)(vb + ks * 32);             // WvT rows v=l15
        t[0][0] = MFMA(a0, b0, t[0][0]); t[0][1] = MFMA(a0, b1, t[0][1]);
        t[0][2] = MFMA(a0, b2, t[0][2]); t[0][3] = MFMA(a0, b3, t[0][3]);
        t[1][0] = MFMA(a1, b0, t[1][0]); t[1][1] = MFMA(a1, b1, t[1][1]);
        t[1][2] = MFMA(a1, b2, t[1][2]); t[1][3] = MFMA(a1, b3, t[1][3]);
        xa[0][0] = MFMA(b0, wf, xa[0][0]);
        xa[0][1] = MFMA(b1, wf, xa[0][1]);
        xa[1][0] = MFMA(b2, wf, xa[1][0]);
        xa[1][1] = MFMA(b3, wf, xa[1][1]);
      }
      // pack t (R4-verbatim) -> scratch [tok-row][e-local]
#pragma unroll
      for (int j = 0; j < 2; ++j)
#pragma unroll
        for (int tt = 0; tt < 4; ++tt) {
          uint2 p;
          PACKU2(p, t[j][tt]);
          *(uint2*)(tb + (tt * 16 + l15) * TS + j * 16 + q4 * 4) = p;
        }
      // pack xa (R4's xv epilogue, verbatim) -> xv_s [v-row l15][tok-col]
#pragma unroll
      for (int i = 0; i < 2; ++i)
#pragma unroll
        for (int mt = 0; mt < 2; ++mt) {
          uint2 p;
          PACKU2(p, xa[i][mt]);
          *(uint2*)(xvb + l15 * TSX + i * 32 + mt * 16 + q4 * 4) = p;
        }
      // s(0): s[l][m] += tT[l][e-chunk0] * x[m][e-chunk0]  (R4-verbatim)
#pragma unroll
      for (int i = 0; i < 2; ++i)
#pragma unroll
        for (int lt = 0; lt < 2; ++lt) {
          v8s ta = *(const v8s*)(tb + ((i * 2 + lt) * 16 + l15) * TS + q4 * 8);
#pragma unroll
          for (int mt = 0; mt < 2; ++mt) {
            v8s xb = *(const v8s*)(
                &x_s[(i * 32 + mt * 16 + l15) * XS + q4 * 8]);  // ch = 0
            s[i][lt][mt] = MFMA(ta, xb, s[i][lt][mt]);
          }
        }
    }

    // ---- chunks 1..9 (R4-verbatim body) ----
#pragma unroll 1
    for (int ch = 1; ch < 10; ++ch) {
      v4f t[2][4];  // [e-tile j][tok-tile tt]
#pragma unroll
      for (int j = 0; j < 2; ++j)
#pragma unroll
        for (int tt = 0; tt < 4; ++tt) t[j][tt] = Z4;
      const bf16u* ap = wqh + (size_t)(ch * 32 + l15) * NEP + q4 * 8;
#pragma unroll
      for (int ks = 0; ks < 10; ++ks) {
        v8s a0 = *(const v8s*)(ap + ks * 32);             // e rows ch*32+0..15
        v8s a1 = *(const v8s*)(ap + 16 * NEP + ks * 32);  // e rows +16..31
        v8s b0 = *(const v8s*)(&x_s[l15 * XS + ks * 32 + q4 * 8]);
        v8s b1 = *(const v8s*)(&x_s[(16 + l15) * XS + ks * 32 + q4 * 8]);
        v8s b2 = *(const v8s*)(&x_s[(32 + l15) * XS + ks * 32 + q4 * 8]);
        v8s b3 = *(const v8s*)(&x_s[(48 + l15) * XS + ks * 32 + q4 * 8]);
        t[0][0] = MFMA(a0, b0, t[0][0]); t[0][1] = MFMA(a0, b1, t[0][1]);
        t[0][2] = MFMA(a0, b2, t[0][2]); t[0][3] = MFMA(a0, b3, t[0][3]);
        t[1][0] = MFMA(a1, b0, t[1][0]); t[1][1] = MFMA(a1, b1, t[1][1]);
        t[1][2] = MFMA(a1, b2, t[1][2]); t[1][3] = MFMA(a1, b3, t[1][3]);
      }
#pragma unroll
      for (int j = 0; j < 2; ++j)
#pragma unroll
        for (int tt = 0; tt < 4; ++tt) {
          uint2 p;
          PACKU2(p, t[j][tt]);
          *(uint2*)(tb + (tt * 16 + l15) * TS + j * 16 + q4 * 4) = p;
        }
#pragma unroll
      for (int i = 0; i < 2; ++i)
#pragma unroll
        for (int lt = 0; lt < 2; ++lt) {
          v8s ta = *(const v8s*)(tb + ((i * 2 + lt) * 16 + l15) * TS + q4 * 8);
#pragma unroll
          for (int mt = 0; mt < 2; ++mt) {
            v8s xb = *(const v8s*)(
                &x_s[(i * 32 + mt * 16 + l15) * XS + ch * 32 + q4 * 8]);
            s[i][lt][mt] = MFMA(ta, xb, s[i][lt][mt]);
          }
        }
    }

    // ---- s -> scratch (bf16 [l-row][m-col], cols 0..31; R4-verbatim) ----
#pragma unroll
    for (int i = 0; i < 2; ++i)
#pragma unroll
      for (int lt = 0; lt < 2; ++lt)
#pragma unroll
        for (int mt = 0; mt < 2; ++mt)
#pragma unroll
          for (int r = 0; r < 4; ++r)
            tb[(i * 32 + lt * 16 + q4 * 4 + r) * TS + mt * 16 + l15] =
                f2b(s[i][lt][mt][r]);

    // ---- softmax over m, in-place (R4-verbatim, 4 passes) ----
#pragma unroll
    for (int p = 0; p < 4; ++p) {
      int row = (p >> 1) * 32 + (p & 1) * 16 + (lane >> 2);
      int jj = lane & 3;
      v8s sv = *(const v8s*)(tb + row * TS + jj * 8);
      float v[8];
      float mx = -1e30f;
#pragma unroll
      for (int k = 0; k < 8; ++k) {
        v[k] = b2f((bf16u)sv[k]) * SCALE;
        mx = fmaxf(mx, v[k]);
      }
      mx = fmaxf(mx, __shfl_xor(mx, 1));
      mx = fmaxf(mx, __shfl_xor(mx, 2));
      float sum = 0.f;
#pragma unroll
      for (int k = 0; k < 8; ++k) { v[k] = __expf(v[k] - mx); sum += v[k]; }
      sum += __shfl_xor(sum, 1);
      sum += __shfl_xor(sum, 2);
      float inv = 1.f / sum;
      bf16u tmp[8];
#pragma unroll
      for (int k = 0; k < 8; ++k) tmp[k] = f2b(v[k] * inv);
      *(uint4*)(tb + row * TS + jj * 8) = *(const uint4*)tmp;
    }

    // ---- v = a @ xv -> val_s[:, h*16 + 0..15] (wave-private columns) ----
#pragma unroll
    for (int i = 0; i < 2; ++i)
#pragma unroll
      for (int lt = 0; lt < 2; ++lt) {
        v8s af = *(const v8s*)(tb + ((i * 2 + lt) * 16 + l15) * TS + q4 * 8);
        v8s bv = *(const v8s*)(xvb + l15 * TSX + i * 32 + q4 * 8);
        v4f vv = MFMA(af, bv, Z4);
#pragma unroll
        for (int r = 0; r < 4; ++r)
          val_s[i * (32 * VS) + (lt * 16 + q4 * 4 + r) * VS + h * 16 + l15] =
              f2b(vv[r]);
      }
  }
  __syncthreads();

  // ---- keyw = tanh(val@WkT + bk); wl = SCALE * qw . keyw (R4 verbatim) ----
  {
    int itm = w >> 2, lt = (w >> 1) & 1, half = w & 1;
    const bf16u* vrow = &val_s[itm * (32 * VS) + (lt * 16 + l15) * VS + q4 * 8];
    v8s af2[8];
#pragma unroll
    for (int ks = 0; ks < 8; ++ks) af2[ks] = *(const v8s*)(vrow + ks * 32);
    float wlp[4] = {0.f, 0.f, 0.f, 0.f};
#pragma unroll
    for (int k = 0; k < 8; ++k) {
      int d = (half * 8 + k) * 16 + l15;
      float bkf = (d < NQD) ? bk[d] : 0.f;
      float qwf = (d < NQD) ? qw[d] : 0.f;
      v4f acc = Z4;
      const bf16u* bp2 = wkT + d * NR + q4 * 8;
#pragma unroll
      for (int ks = 0; ks < 8; ++ks) {
        v8s b = *(const v8s*)(bp2 + ks * 32);
        acc = MFMA(af2[ks], b, acc);
      }
#pragma unroll
      for (int r = 0; r < 4; ++r)
        wlp[r] += tanhf(acc[r] + bkf) * qwf;
    }
#pragma unroll
    for (int r = 0; r < 4; ++r) {
      float tv = wlp[r] * SCALE;
      tv += __shfl_xor(tv, 1);
      tv += __shfl_xor(tv, 2);
      tv += __shfl_xor(tv, 4);
      tv += __shfl_xor(tv, 8);
      if (l15 == 0) wl_s[half][itm * 32 + lt * 16 + q4 * 4 + r] = tv;
    }
  }
  __syncthreads();

  // ---- ww = softmax(wl) per item (lanes 0-31 item0, 32-63 item1) ----
  if (tid < 64) {
    float v = wl_s[0][tid] + wl_s[1][tid];
    float mx = v;
#pragma unroll
    for (int off = 1; off < 32; off <<= 1) mx = fmaxf(mx, __shfl_xor(mx, off, 32));
    float e = __expf(v - mx);
    float sum = e;
#pragma unroll
    for (int off = 1; off < 32; off <<= 1) sum += __shfl_xor(sum, off, 32);
    ww_s[tid] = e / sum;
  }
  __syncthreads();

  // ---- rep[r] = sum_l ww[l]*val[l][r] ----
  {
    int itm = tid >> 8, r = tid & 255;
    const bf16u* vb2 = &val_s[itm * (32 * VS) + r];
    float sv = 0.f;
#pragma unroll 8
    for (int l = 0; l < 32; ++l) sv += ww_s[itm * 32 + l] * b2f(vb2[l * VS]);
    rep[(size_t)(g0 + itm) * NR + r] = sv;
  }
  // ---- hval writeback (clicked items only), coalesced uint4 ----
  if (g0 >= NB * NCDD) {
    for (int c = tid; c < 2048; c += 512) {
      int itm = c >> 10, l = (c >> 5) & 31, j = c & 31;
      *(uint4*)(hval + (size_t)(g0 + itm) * (NL * NR) + l * NR + j * 8) =
          *(const uint4*)(&val_s[itm * (32 * VS) + l * VS + j * 8]);
    }
  }
}

// ---------------------------------------------------------------------------
// select: one block per (b,c): score[h] = cdd_rep.his_rep + gumbel (h<40),
// argmax, gather. grid = 160.
// ---------------------------------------------------------------------------
__global__ __launch_bounds__(256) void select_kernel(
    const float* __restrict__ rep, const float* __restrict__ gumbel,
    const bf16u* __restrict__ hval, float* __restrict__ out) {
  __shared__ float score[NMASK];
  __shared__ int hstar;
  const float* cdd_rep = rep;
  const float* his_rep = rep + (size_t)(NB * NCDD) * NR;
  const bf16u* his_val = hval + (size_t)(NB * NCDD) * (NL * NR);
  int b = blockIdx.x / NCDD, c = blockIdx.x % NCDD;
  int tid = threadIdx.x, lane = tid & 63, wv = tid >> 6;
  const float* cr = cdd_rep + (size_t)(b * NCDD + c) * NR;
  for (int h = wv; h < NMASK; h += 4) {
    const float* hr = his_rep + (size_t)(b * NHIS + h) * NR;
    float s = 0.f;
#pragma unroll
    for (int j = 0; j < 4; ++j) s += cr[lane * 4 + j] * hr[lane * 4 + j];
#pragma unroll
    for (int off = 1; off < 64; off <<= 1) s += __shfl_xor(s, off);
    if (lane == 0)
      score[h] = s + gumbel[(b * NCDD + c) * NHIS + h];
  }
  __syncthreads();
  if (tid == 0) {
    float best = -1e30f;
    int bi = 0;
    for (int h = 0; h < NMASK; ++h) {
      float v = score[h];
      if (v > best) { best = v; bi = h; }  // strict > keeps first max
    }
    hstar = bi;
  }
  __syncthreads();
  const bf16u* src = his_val + (size_t)(b * NHIS + hstar) * (NL * NR);
  float* dst = out + (size_t)(b * NCDD + c) * (NL * NR);
  for (int k = tid; k < 2048; k += 256) {
    const bf16u* sp = src + k * 4;
    float4 o;
    o.x = b2f(sp[0]); o.y = b2f(sp[1]); o.z = b2f(sp[2]); o.w = b2f(sp[3]);
    *(float4*)(dst + k * 4) = o;
  }
}

extern "C" void kernel_launch(void* const* d_in, const int* in_sizes, int n_in,
                              void* d_out, int out_size, void* d_ws, size_t ws_size,
                              hipStream_t stream) {
  (void)in_sizes; (void)n_in; (void)out_size; (void)ws_size;
  const int* cand = (const int*)d_in[0];
  const int* clk = (const int*)d_in[1];
  // d_in[2] his_mask (static: h>=40), d_in[3]/d_in[4] pads: unused
  const float* gum = (const float*)d_in[5];
  const float* emb = (const float*)d_in[6];
  const float* wq = (const float*)d_in[7];
  const float* wvp = (const float*)d_in[8];
  const float* wk = (const float*)d_in[9];
  const float* bk = (const float*)d_in[10];
  const float* qw = (const float*)d_in[11];

  char* ws = (char*)d_ws;
  bf16u* wqB = (bf16u*)(ws + WQB_OFF);
  bf16u* wvT = (bf16u*)(ws + WVT_OFF);
  bf16u* wkT = (bf16u*)(ws + WKT_OFF);
  float* rep = (float*)(ws + REP_OFF);
  bf16u* hval = (bf16u*)(ws + HVAL_OFF);

  const int totalT = 16 * 320 * 320 + 16 * 16 * 320 + 256 * 256;  // 1,785,856
  hipLaunchKernelGGL(prep_kernel, dim3((totalT + 255) / 256), dim3(256), 0, stream,
                     wq, wvp, wk, wqB, wvT, wkT);
  hipLaunchKernelGGL(encode_kernel, dim3(NITEM / 2), dim3(512), 0, stream,
                     cand, clk, emb, wqB, wvT, wkT, bk, qw, rep, hval);
  hipLaunchKernelGGL(select_kernel, dim3(NB * NCDD), dim3(256), 0, stream,
                     rep, gum, hval, (float*)d_out);
}

// Round 11
// 595.244 us; speedup vs baseline: 1.6171x; 1.0550x over previous
//
#include <hip/hip_runtime.h>
#include <hip/hip_bf16.h>

typedef short v8s __attribute__((ext_vector_type(8)));
typedef short v4s __attribute__((ext_vector_type(4)));
typedef float v4f __attribute__((ext_vector_type(4)));
typedef unsigned short bf16u;

#define NB    32
#define NCDD  5
#define NHIS  50
#define NL    32
#define NE    300
#define NEP   320
#define NH    16
#define NQD   200
#define NR    256
#define NMASK 40
#define NITEM 1760
#define SCALE 0.05773502691896258f  /* 1/sqrt(300) */

// workspace offsets (bytes), all 256-aligned
#define WQB_OFF  0u          /* wqB [16][320][320] bf16 = 3,276,800 ([h][e][f]) */
#define WVT_OFF  3276800u    /* wvT [16][16][320]  bf16 =   163,840 */
#define WKT_OFF  3440640u    /* wkT [256][256]     bf16 =   131,072 */
#define REP_OFF  3571712u    /* rep [1760][256]    f32  = 1,802,240 */
#define HVAL_OFF 5373952u    /* hval [1760][32][256] bf16 = 28,835,840 */

#define XS  328  /* x LDS row stride: 656B -> 2-way bank step (free) */
#define VS  264  /* val row stride: 528B, 16B-aligned */

__device__ __forceinline__ float b2f(bf16u u) {
  return __uint_as_float(((unsigned int)u) << 16);
}
// native RNE convert (R7/R10: absmax unchanged vs manual RNE; fuses to cvt_pk)
__device__ __forceinline__ bf16u f2b(float f) {
  __hip_bfloat16 h = __float2bfloat16(f);
  return *reinterpret_cast<bf16u*>(&h);
}

#define MFMA(a, b, c) __builtin_amdgcn_mfma_f32_16x16x32_bf16((a), (b), (c), 0, 0, 0)
// K=16 bf16 MFMA (carried forward from gfx90a; instruction v_mfma_f32_16x16x16_bf16
// per cdna4_isa.md §10). A/B frag: [own=lane&15][k=(lane>>4)*4+j]; C/D: as 16x16x32.
#define MFMA16(a, b, c) __builtin_amdgcn_mfma_f32_16x16x16bf16_1k((a), (b), (c), 0, 0, 0)
#define Z4 ((v4f){0.f, 0.f, 0.f, 0.f})

// v4f acc tile -> bf16 K=16 fragment (in-register; replaces LDS round-trip)
__device__ __forceinline__ v4s cvt4(v4f t) {
  v4s r;
  r[0] = (short)f2b(t[0]); r[1] = (short)f2b(t[1]);
  r[2] = (short)f2b(t[2]); r[3] = (short)f2b(t[3]);
  return r;
}

// ---------------------------------------------------------------------------
// prep: f32 weights -> bf16, zero-padded.
// ---------------------------------------------------------------------------
__global__ void prep_kernel(const float* __restrict__ wq,
                            const float* __restrict__ wvp,
                            const float* __restrict__ wk,
                            bf16u* __restrict__ wqB,
                            bf16u* __restrict__ wvT,
                            bf16u* __restrict__ wkT) {
  int idx = blockIdx.x * 256 + threadIdx.x;
  const int N1 = 16 * 320 * 320;
  const int N2 = 16 * 16 * 320;
  const int N3 = 256 * 256;
  if (idx < N1) {
    int h = idx / (320 * 320);
    int r = idx % (320 * 320);
    int e = r / 320, f = r % 320;
    wqB[idx] = (e < NE && f < NE) ? f2b(wq[h * 90000 + e * 300 + f]) : (bf16u)0;
  } else if (idx < N1 + N2) {
    int i = idx - N1;
    int h = i / (16 * 320);
    int r = i % (16 * 320);
    int v = r / 320, e = r % 320;
    wvT[i] = (e < NE) ? f2b(wvp[h * 4800 + e * 16 + v]) : (bf16u)0;
  } else if (idx < N1 + N2 + N3) {
    int i = idx - N1 - N2;
    int d = i / 256, rr = i % 256;
    wkT[i] = (d < NQD) ? f2b(wk[rr * 200 + d]) : (bf16u)0;
  }
}

// ---------------------------------------------------------------------------
// encode: grid = 880 2-item blocks; 512 thr (8 waves); 76.5 KB LDS.
// ROUND-11: delete the per-chunk LDS round-trip via MFMA fragment algebra.
// R4-R10 all paid {pack -> ds_write -> lgkm -> ds_read -> MFMA} x20 chunks;
// pipelining it away always spilled. Instead use K=16 MFMA layout identities:
//  * t acc D-layout [col=tok=l15][row=e=4q4+r] IS a K=16 B-frag (r<->j):
//    q-frags = cvt4(t) in-register, zero LDS.
//  * sT = MFMA16(x_frag, q_frag): D [row=m-local][col=l=l15] -> softmax over
//    m is in-register: 8 lane-local vals + shfl_xor(16,32) across q4 groups.
//  * a (post-softmax) sits exactly in v-GEMM A-frag-16 form [row=l=l15]
//    [k=m=4q4+j]; xv acc D [row=tok=4q4+r][col=v=l15] is exactly v-GEMM's
//    B-frag-16. v = MFMA16(a, xv) -> val_s write identical to R10's.
// Head loop touches LDS only for read-only x_s. scr_s + xv_s deleted:
// LDS 136 -> 76.5 KB; if VGPR <= 128 (R10: exactly 128 with more state),
// 2 blocks/CU co-reside under (512,2) -> 4 waves/SIMD.
// s-MFMAs double (K=16) -- noise vs 800 t-MFMAs/head. Softmax now on f32 s
// (no bf16 round-trip) -- strictly closer to the JAX ref.
// Tail keyw/ww/rep/hval + select: R10-verbatim.
// ---------------------------------------------------------------------------
__global__ __launch_bounds__(512, 2) void encode_kernel(
    const int* __restrict__ cand_tok, const int* __restrict__ clk_tok,
    const float* __restrict__ emb,
    const bf16u* __restrict__ wqB, const bf16u* __restrict__ wvT,
    const bf16u* __restrict__ wkT,
    const float* __restrict__ bk, const float* __restrict__ qw,
    float* __restrict__ rep, bf16u* __restrict__ hval) {
  __shared__ alignas(16) bf16u x_s[64 * XS];        // 41,984 B
  __shared__ alignas(16) bf16u val_s[2 * 32 * VS];  // 33,792 B
  __shared__ float wl_s[2][64];                     //    512 B
  __shared__ float ww_s[64];                        //    256 B
  // total 76,544 B -> 2 blocks/CU if VGPR <= 128

  const int tid = threadIdx.x;
  const int lane = tid & 63;
  const int w = tid >> 6;     // wave 0..7
  const int q4 = lane >> 4;
  const int l15 = lane & 15;
  const int g0 = blockIdx.x * 2;

  // gather 2 items of x straight from emb (f32 -> bf16), pad cols 300..327
  for (int c = tid; c < 2 * 32 * 82; c += 512) {
    int item = c / (32 * 82);
    int rr = c % (32 * 82);
    int l = rr / 82, j = rr % 82;
    bf16u tmp[4] = {0, 0, 0, 0};
    if (j < 75) {
      int gi = g0 + item;
      int tok = (gi < NB * NCDD) ? cand_tok[gi * NL + l]
                                 : clk_tok[(gi - NB * NCDD) * NL + l];
      float4 d = *(const float4*)(emb + (size_t)tok * NE + j * 4);
      tmp[0] = f2b(d.x); tmp[1] = f2b(d.y); tmp[2] = f2b(d.z); tmp[3] = f2b(d.w);
    }
    *(uint2*)(&x_s[item * 32 * XS + l * XS + j * 4]) = *(const uint2*)tmp;
  }
  __syncthreads();

  for (int hh = 0; hh < 2; ++hh) {
    const int h = (w << 1) | hh;
    const bf16u* wqh = wqB + (size_t)h * 102400;

    // sT accumulators: [item i][m-tile mt][l-tile lt]; lane holds
    // sT[m=(2i+mt)*16+4q4+r][l=(2i+lt)*16+l15]
    v4f sT[2][2][2];
#pragma unroll
    for (int i = 0; i < 2; ++i)
#pragma unroll
      for (int mt = 0; mt < 2; ++mt)
#pragma unroll
        for (int lt = 0; lt < 2; ++lt) sT[i][mt][lt] = Z4;

#pragma unroll 1
    for (int ch = 0; ch < 10; ++ch) {
      // ---- t-chunk (R10-verbatim): t[e=ch*32..+31][tok 0..63] = Wq @ x^T ----
      v4f t[2][4];  // [e-subtile j][tok-tile tt]
#pragma unroll
      for (int j = 0; j < 2; ++j)
#pragma unroll
        for (int tt = 0; tt < 4; ++tt) t[j][tt] = Z4;
      const bf16u* ap = wqh + (size_t)(ch * 32 + l15) * NEP + q4 * 8;
#pragma unroll
      for (int ks = 0; ks < 10; ++ks) {
        v8s a0 = *(const v8s*)(ap + ks * 32);             // e rows ch*32+0..15
        v8s a1 = *(const v8s*)(ap + 16 * NEP + ks * 32);  // e rows +16..31
        v8s b0 = *(const v8s*)(&x_s[l15 * XS + ks * 32 + q4 * 8]);
        v8s b1 = *(const v8s*)(&x_s[(16 + l15) * XS + ks * 32 + q4 * 8]);
        v8s b2 = *(const v8s*)(&x_s[(32 + l15) * XS + ks * 32 + q4 * 8]);
        v8s b3 = *(const v8s*)(&x_s[(48 + l15) * XS + ks * 32 + q4 * 8]);
        t[0][0] = MFMA(a0, b0, t[0][0]); t[0][1] = MFMA(a0, b1, t[0][1]);
        t[0][2] = MFMA(a0, b2, t[0][2]); t[0][3] = MFMA(a0, b3, t[0][3]);
        t[1][0] = MFMA(a1, b0, t[1][0]); t[1][1] = MFMA(a1, b1, t[1][1]);
        t[1][2] = MFMA(a1, b2, t[1][2]); t[1][3] = MFMA(a1, b3, t[1][3]);
      }
      // ---- t acc -> K=16 B-frags IN REGISTER (the deleted round-trip) ----
      // qf[subk][tt]: B[col=tok-in-tile tt][k=e-local of subtile subk]
      v4s qf[2][4];
#pragma unroll
      for (int j = 0; j < 2; ++j)
#pragma unroll
        for (int tt = 0; tt < 4; ++tt) qf[j][tt] = cvt4(t[j][tt]);
      // ---- sT += x_frag @ qf over this chunk's 32 e (2 K=16 subtiles) ----
#pragma unroll
      for (int i = 0; i < 2; ++i)
#pragma unroll
        for (int mt = 0; mt < 2; ++mt)
#pragma unroll
          for (int subk = 0; subk < 2; ++subk) {
            // A-frag: x[m=(2i+mt)*16+l15][e=ch*32+subk*16+4q4+j] (b64)
            v4s xa = *(const v4s*)(
                &x_s[((i * 2 + mt) * 16 + l15) * XS + ch * 32 + subk * 16 +
                     q4 * 4]);
            sT[i][mt][0] = MFMA16(xa, qf[subk][i * 2 + 0], sT[i][mt][0]);
            sT[i][mt][1] = MFMA16(xa, qf[subk][i * 2 + 1], sT[i][mt][1]);
          }
    }

    // ---- softmax over m, fully in-register (rows l = l15, lane-local
    //      m = mt*16 + 4q4 + r; cross-q4 via shfl_xor 16/32) ----
    // af[i][mt][lt]: v-GEMM A-frag-16 = a[l=l15][m-local=4q4+j of tile mt]
    v4s af[2][2][2];
#pragma unroll
    for (int i = 0; i < 2; ++i)
#pragma unroll
      for (int lt = 0; lt < 2; ++lt) {
        float pv[2][4];
        float mx = -1e30f;
#pragma unroll
        for (int mt = 0; mt < 2; ++mt)
#pragma unroll
          for (int r = 0; r < 4; ++r) {
            pv[mt][r] = sT[i][mt][lt][r] * SCALE;
            mx = fmaxf(mx, pv[mt][r]);
          }
        mx = fmaxf(mx, __shfl_xor(mx, 16));
        mx = fmaxf(mx, __shfl_xor(mx, 32));
        float sum = 0.f;
#pragma unroll
        for (int mt = 0; mt < 2; ++mt)
#pragma unroll
          for (int r = 0; r < 4; ++r) {
            pv[mt][r] = __expf(pv[mt][r] - mx);
            sum += pv[mt][r];
          }
        sum += __shfl_xor(sum, 16);
        sum += __shfl_xor(sum, 32);
        float inv = 1.f / sum;
#pragma unroll
        for (int mt = 0; mt < 2; ++mt) {
          v4s a;
          a[0] = (short)f2b(pv[mt][0] * inv);
          a[1] = (short)f2b(pv[mt][1] * inv);
          a[2] = (short)f2b(pv[mt][2] * inv);
          a[3] = (short)f2b(pv[mt][3] * inv);
          af[i][mt][lt] = a;
        }
      }

    // ---- xv = x @ WvT[h] (K=32, acc in register; both items) ----
    v4f xva[2][2];  // [item][m-tile]: D [row=tok-local=4q4+r][col=v=l15]
#pragma unroll
    for (int i = 0; i < 2; ++i)
#pragma unroll
      for (int mt = 0; mt < 2; ++mt) xva[i][mt] = Z4;
    {
      const bf16u* vb = wvT + (size_t)h * (16 * NEP) + l15 * NEP + q4 * 8;
#pragma unroll
      for (int ks = 0; ks < 10; ++ks) {
        v8s b = *(const v8s*)(vb + ks * 32);
#pragma unroll
        for (int i = 0; i < 2; ++i)
#pragma unroll
          for (int mt = 0; mt < 2; ++mt) {
            v8s a = *(const v8s*)(
                &x_s[(i * 32 + mt * 16 + l15) * XS + ks * 32 + q4 * 8]);
            xva[i][mt] = MFMA(a, b, xva[i][mt]);
          }
      }
    }
    // xv acc IS the v-GEMM B-frag-16: B[col=v=l15][k=m-local=4q4+j]
    v4s xvf[2][2];
#pragma unroll
    for (int i = 0; i < 2; ++i)
#pragma unroll
      for (int mt = 0; mt < 2; ++mt) xvf[i][mt] = cvt4(xva[i][mt]);

    // ---- v = a @ xv (2x K=16) -> val_s[:, h*16..+15] (R10-identical write) ----
#pragma unroll
    for (int i = 0; i < 2; ++i)
#pragma unroll
      for (int lt = 0; lt < 2; ++lt) {
        v4f vo = MFMA16(af[i][0][lt], xvf[i][0], Z4);
        vo = MFMA16(af[i][1][lt], xvf[i][1], vo);
#pragma unroll
        for (int r = 0; r < 4; ++r)
          val_s[i * (32 * VS) + (lt * 16 + q4 * 4 + r) * VS + h * 16 + l15] =
              f2b(vo[r]);
      }
  }
  __syncthreads();

  // ---- keyw = tanh(val@WkT + bk); wl = SCALE * qw . keyw (R10 verbatim) ----
  {
    int itm = w >> 2, lt = (w >> 1) & 1, half = w & 1;
    const bf16u* vrow = &val_s[itm * (32 * VS) + (lt * 16 + l15) * VS + q4 * 8];
    v8s af2[8];
#pragma unroll
    for (int ks = 0; ks < 8; ++ks) af2[ks] = *(const v8s*)(vrow + ks * 32);
    float wlp[4] = {0.f, 0.f, 0.f, 0.f};
#pragma unroll
    for (int k = 0; k < 8; ++k) {
      int d = (half * 8 + k) * 16 + l15;
      float bkf = (d < NQD) ? bk[d] : 0.f;
      float qwf = (d < NQD) ? qw[d] : 0.f;
      v4f acc = Z4;
      const bf16u* bp2 = wkT + d * NR + q4 * 8;
#pragma unroll
      for (int ks = 0; ks < 8; ++ks) {
        v8s b = *(const v8s*)(bp2 + ks * 32);
        acc = MFMA(af2[ks], b, acc);
      }
#pragma unroll
      for (int r = 0; r < 4; ++r)
        wlp[r] += tanhf(acc[r] + bkf) * qwf;
    }
#pragma unroll
    for (int r = 0; r < 4; ++r) {
      float tv = wlp[r] * SCALE;
      tv += __shfl_xor(tv, 1);
      tv += __shfl_xor(tv, 2);
      tv += __shfl_xor(tv, 4);
      tv += __shfl_xor(tv, 8);
      if (l15 == 0) wl_s[half][itm * 32 + lt * 16 + q4 * 4 + r] = tv;
    }
  }
  __syncthreads();

  // ---- ww = softmax(wl) per item (lanes 0-31 item0, 32-63 item1) ----
  if (tid < 64) {
    float v = wl_s[0][tid] + wl_s[1][tid];
    float mx = v;
#pragma unroll
    for (int off = 1; off < 32; off <<= 1) mx = fmaxf(mx, __shfl_xor(mx, off, 32));
    float e = __expf(v - mx);
    float sum = e;
#pragma unroll
    for (int off = 1; off < 32; off <<= 1) sum += __shfl_xor(sum, off, 32);
    ww_s[tid] = e / sum;
  }
  __syncthreads();

  // ---- rep[r] = sum_l ww[l]*val[l][r] ----
  {
    int itm = tid >> 8, r = tid & 255;
    const bf16u* vb2 = &val_s[itm * (32 * VS) + r];
    float sv = 0.f;
#pragma unroll 8
    for (int l = 0; l < 32; ++l) sv += ww_s[itm * 32 + l] * b2f(vb2[l * VS]);
    rep[(size_t)(g0 + itm) * NR + r] = sv;
  }
  // ---- hval writeback (clicked items only), coalesced uint4 ----
  if (g0 >= NB * NCDD) {
    for (int c = tid; c < 2048; c += 512) {
      int itm = c >> 10, l = (c >> 5) & 31, j = c & 31;
      *(uint4*)(hval + (size_t)(g0 + itm) * (NL * NR) + l * NR + j * 8) =
          *(const uint4*)(&val_s[itm * (32 * VS) + l * VS + j * 8]);
    }
  }
}

// ---------------------------------------------------------------------------
// select: one block per (b,c): score[h] = cdd_rep.his_rep + gumbel (h<40),
// argmax, gather. grid = 160.
// ---------------------------------------------------------------------------
__global__ __launch_bounds__(256) void select_kernel(
    const float* __restrict__ rep, const float* __restrict__ gumbel,
    const bf16u* __restrict__ hval, float* __restrict__ out) {
  __shared__ float score[NMASK];
  __shared__ int hstar;
  const float* cdd_rep = rep;
  const float* his_rep = rep + (size_t)(NB * NCDD) * NR;
  const bf16u* his_val = hval + (size_t)(NB * NCDD) * (NL * NR);
  int b = blockIdx.x / NCDD, c = blockIdx.x % NCDD;
  int tid = threadIdx.x, lane = tid & 63, wv = tid >> 6;
  const float* cr = cdd_rep + (size_t)(b * NCDD + c) * NR;
  for (int h = wv; h < NMASK; h += 4) {
    const float* hr = his_rep + (size_t)(b * NHIS + h) * NR;
    float s = 0.f;
#pragma unroll
    for (int j = 0; j < 4; ++j) s += cr[lane * 4 + j] * hr[lane * 4 + j];
#pragma unroll
    for (int off = 1; off < 64; off <<= 1) s += __shfl_xor(s, off);
    if (lane == 0)
      score[h] = s + gumbel[(b * NCDD + c) * NHIS + h];
  }
  __syncthreads();
  if (tid == 0) {
    float best = -1e30f;
    int bi = 0;
    for (int h = 0; h < NMASK; ++h) {
      float v = score[h];
      if (v > best) { best = v; bi = h; }  // strict > keeps first max
    }
    hstar = bi;
  }
  __syncthreads();
  const bf16u* src = his_val + (size_t)(b * NHIS + hstar) * (NL * NR);
  float* dst = out + (size_t)(b * NCDD + c) * (NL * NR);
  for (int k = tid; k < 2048; k += 256) {
    const bf16u* sp = src + k * 4;
    float4 o;
    o.x = b2f(sp[0]); o.y = b2f(sp[1]); o.z = b2f(sp[2]); o.w = b2f(sp[3]);
    *(float4*)(dst + k * 4) = o;
  }
}

extern "C" void kernel_launch(void* const* d_in, const int* in_sizes, int n_in,
                              void* d_out, int out_size, void* d_ws, size_t ws_size,
                              hipStream_t stream) {
  (void)in_sizes; (void)n_in; (void)out_size; (void)ws_size;
  const int* cand = (const int*)d_in[0];
  const int* clk = (const int*)d_in[1];
  // d_in[2] his_mask (static: h>=40), d_in[3]/d_in[4] pads: unused
  const float* gum = (const float*)d_in[5];
  const float* emb = (const float*)d_in[6];
  const float* wq = (const float*)d_in[7];
  const float* wvp = (const float*)d_in[8];
  const float* wk = (const float*)d_in[9];
  const float* bk = (const float*)d_in[10];
  const float* qw = (const float*)d_in[11];

  char* ws = (char*)d_ws;
  bf16u* wqB = (bf16u*)(ws + WQB_OFF);
  bf16u* wvT = (bf16u*)(ws + WVT_OFF);
  bf16u* wkT = (bf16u*)(ws + WKT_OFF);
  float* rep = (float*)(ws + REP_OFF);
  bf16u* hval = (bf16u*)(ws + HVAL_OFF);

  const int totalT = 16 * 320 * 320 + 16 * 16 * 320 + 256 * 256;  // 1,785,856
  hipLaunchKernelGGL(prep_kernel, dim3((totalT + 255) / 256), dim3(256), 0, stream,
                     wq, wvp, wk, wqB, wvT, wkT);
  hipLaunchKernelGGL(encode_kernel, dim3(NITEM / 2), dim3(512), 0, stream,
                     cand, clk, emb, wqB, wvT, wkT, bk, qw, rep, hval);
  hipLaunchKernelGGL(select_kernel, dim3(NB * NCDD), dim3(256), 0, stream,
                     rep, gum, hval, (float*)d_out);
}